// Round 18
// baseline (87.460 us; speedup 1.0000x reference)
//
#include <hip/hip_runtime.h>
#include <hip/hip_bf16.h>
#include <hip/hip_fp16.h>

#define NTOK 2048
#define DDIM 512
#define NBATCH 8

using bf16x8 = __attribute__((ext_vector_type(8))) short;
using f32x4  = __attribute__((ext_vector_type(4))) float;

__device__ __forceinline__ short f2bf(float f) {
  __hip_bfloat16 h = __float2bfloat16(f);
  union { __hip_bfloat16 h; short s; } u; u.h = h;
  return u.s;
}

__device__ __forceinline__ float e5m2tof(unsigned byte) {
  // e5m2 is f16 truncated to its top 8 bits
  union { unsigned short u; __half h; } c;
  c.u = (unsigned short)(byte << 8);
  return __half2float(c.h);
}

__device__ __forceinline__ void async_copy16(void* lds, const void* g) {
  __builtin_amdgcn_global_load_lds(
      (const __attribute__((address_space(1))) void*)g,
      (__attribute__((address_space(3))) void*)lds,
      16, 0, 0);
}

// fp32 -> fp8 e4m3 (OCP) convert: each thread 8 floats -> 8 B store.
__global__ __launch_bounds__(256) void convert_fp8_kernel(const float* __restrict__ X,
                                                          char* __restrict__ Y) {
  const int i = blockIdx.x * 256 + threadIdx.x;
  const float4* xv = reinterpret_cast<const float4*>(X);
  const float4 a = xv[(size_t)i * 2];
  const float4 b = xv[(size_t)i * 2 + 1];
  int lo = __builtin_amdgcn_cvt_pk_fp8_f32(a.x, a.y, 0, false);
  lo     = __builtin_amdgcn_cvt_pk_fp8_f32(a.z, a.w, lo, true);
  int hi = __builtin_amdgcn_cvt_pk_fp8_f32(b.x, b.y, 0, false);
  hi     = __builtin_amdgcn_cvt_pk_fp8_f32(b.z, b.w, hi, true);
  int2 o; o.x = lo; o.y = hi;
  *reinterpret_cast<int2*>(Y + (size_t)i * 8) = o;
}

// Symmetric scores on fp8-e4m3 (r17 champion, unchanged): 128x128 tile,
// 4 waves, BK=64 + XOR swizzle, 3-slot ring, one barrier per K-step,
// e5m2 output, diag alias B->A.
__global__ __launch_bounds__(256, 4) void scores_fp8_kernel(
    const char* __restrict__ X8, char* __restrict__ S8) {
  int rem = blockIdx.x >> 3;
  int bi = 0;
  while (rem >= 16 - bi) { rem -= 16 - bi; ++bi; }
  const int bj = bi + rem;
  const int b  = blockIdx.x & 7;           // batch -> XCD pin
  const bool diag = (bi == bj);

  const int i0 = bi * 128;
  const int j0 = bj * 128;
  const char* Xb = X8 + (size_t)b * NTOK * DDIM;   // 512 B per row
  char* Sb = S8 + (size_t)b * NTOK * NTOK;         // 1 B per score

  __shared__ char ldsA8[3][128 * 64];      // 8 KB per slot
  __shared__ char ldsB8[3][128 * 64];      // total 48 KB

  const int t    = threadIdx.x;
  const int lane = t & 63;
  const int w    = t >> 6;                 // 0..3
  const int wr   = (w >> 1) * 64;
  const int wc   = (w & 1) * 64;
  const int lr   = lane & 15;
  const int g    = lane >> 4;              // 0..3
  const int s4   = (lr >> 2) & 3;          // read-side swizzle key (row>>2)&3
  const int ko0  = (((g >> 1) ^ s4) * 16) + (g & 1) * 8;
  const int ko1  = (((2 + (g >> 1)) ^ s4) * 16) + (g & 1) * 8;

  f32x4 acc[4][4] = {};

  auto stage8 = [&](int slot, int kt) {
    const int k0 = kt * 64;                // 64 B per row per K-step
#pragma unroll
    for (int q = 0; q < 2; ++q) {
      const int seg  = w * 2 + q;          // 8 segs of 1 KB (16 rows x 64 B)
      const int row  = seg * 16 + (lane >> 2);
      const int csrc = ((lane & 3) ^ ((row >> 2) & 3)) * 16;  // inverse swizzle
      async_copy16(&ldsA8[slot][seg * 1024],
                   Xb + (size_t)(i0 + row) * DDIM + k0 + csrc);
      if (!diag)
        async_copy16(&ldsB8[slot][seg * 1024],
                     Xb + (size_t)(j0 + row) * DDIM + k0 + csrc);
    }
  };

  auto phases8 = [&](int slot) {
    const char* A0 = ldsA8[slot];
    const char* B0 = diag ? ldsA8[slot] : ldsB8[slot];
#pragma unroll
    for (int ks = 0; ks < 2; ++ks) {
      const int ko = ks ? ko1 : ko0;
      long long af0 = *reinterpret_cast<const long long*>(&A0[(wr + 0 * 16 + lr) * 64 + ko]);
      long long af1 = *reinterpret_cast<const long long*>(&A0[(wr + 1 * 16 + lr) * 64 + ko]);
      long long af2 = *reinterpret_cast<const long long*>(&A0[(wr + 2 * 16 + lr) * 64 + ko]);
      long long af3 = *reinterpret_cast<const long long*>(&A0[(wr + 3 * 16 + lr) * 64 + ko]);
      long long bf0 = *reinterpret_cast<const long long*>(&B0[(wc + 0 * 16 + lr) * 64 + ko]);
      long long bf1 = *reinterpret_cast<const long long*>(&B0[(wc + 1 * 16 + lr) * 64 + ko]);
      long long bf2 = *reinterpret_cast<const long long*>(&B0[(wc + 2 * 16 + lr) * 64 + ko]);
      long long bf3 = *reinterpret_cast<const long long*>(&B0[(wc + 3 * 16 + lr) * 64 + ko]);
      __builtin_amdgcn_s_setprio(1);
      acc[0][0] = __builtin_amdgcn_mfma_f32_16x16x32_fp8_fp8(af0, bf0, acc[0][0], 0, 0, 0);
      acc[0][1] = __builtin_amdgcn_mfma_f32_16x16x32_fp8_fp8(af0, bf1, acc[0][1], 0, 0, 0);
      acc[0][2] = __builtin_amdgcn_mfma_f32_16x16x32_fp8_fp8(af0, bf2, acc[0][2], 0, 0, 0);
      acc[0][3] = __builtin_amdgcn_mfma_f32_16x16x32_fp8_fp8(af0, bf3, acc[0][3], 0, 0, 0);
      acc[1][0] = __builtin_amdgcn_mfma_f32_16x16x32_fp8_fp8(af1, bf0, acc[1][0], 0, 0, 0);
      acc[1][1] = __builtin_amdgcn_mfma_f32_16x16x32_fp8_fp8(af1, bf1, acc[1][1], 0, 0, 0);
      acc[1][2] = __builtin_amdgcn_mfma_f32_16x16x32_fp8_fp8(af1, bf2, acc[1][2], 0, 0, 0);
      acc[1][3] = __builtin_amdgcn_mfma_f32_16x16x32_fp8_fp8(af1, bf3, acc[1][3], 0, 0, 0);
      acc[2][0] = __builtin_amdgcn_mfma_f32_16x16x32_fp8_fp8(af2, bf0, acc[2][0], 0, 0, 0);
      acc[2][1] = __builtin_amdgcn_mfma_f32_16x16x32_fp8_fp8(af2, bf1, acc[2][1], 0, 0, 0);
      acc[2][2] = __builtin_amdgcn_mfma_f32_16x16x32_fp8_fp8(af2, bf2, acc[2][2], 0, 0, 0);
      acc[2][3] = __builtin_amdgcn_mfma_f32_16x16x32_fp8_fp8(af2, bf3, acc[2][3], 0, 0, 0);
      acc[3][0] = __builtin_amdgcn_mfma_f32_16x16x32_fp8_fp8(af3, bf0, acc[3][0], 0, 0, 0);
      acc[3][1] = __builtin_amdgcn_mfma_f32_16x16x32_fp8_fp8(af3, bf1, acc[3][1], 0, 0, 0);
      acc[3][2] = __builtin_amdgcn_mfma_f32_16x16x32_fp8_fp8(af3, bf2, acc[3][2], 0, 0, 0);
      acc[3][3] = __builtin_amdgcn_mfma_f32_16x16x32_fp8_fp8(af3, bf3, acc[3][3], 0, 0, 0);
      __builtin_amdgcn_s_setprio(0);
    }
  };

  // prologue: stage kt=0 into slot 0 (prefetch depth 1)
  stage8(0, 0);
#pragma unroll
  for (int i = 0; i < 8; ++i) {
    if (i + 1 < 8) {
      stage8((i + 1) % 3, i + 1);          // issue next-tile loads first
      if (diag) { asm volatile("s_waitcnt vmcnt(2)" ::: "memory"); }
      else      { asm volatile("s_waitcnt vmcnt(4)" ::: "memory"); }
    } else {
      asm volatile("s_waitcnt vmcnt(0)" ::: "memory");
    }
    __builtin_amdgcn_s_barrier();          // slot i visible to all waves
    phases8(i % 3);                        // single barrier per K-step
  }

  // epilogue: C/D layout col = lane&15, row = (lane>>4)*4 + reg.
  const int crow = (lane >> 4) * 4;
  const int ccol = lane & 15;

#pragma unroll
  for (int m = 0; m < 4; ++m) {
#pragma unroll
    for (int n = 0; n < 4; ++n) {
      const int gr = i0 + wr + m * 16 + crow;   // multiple of 4
      const int gc = j0 + wc + n * 16 + ccol;
      int pk = __builtin_amdgcn_cvt_pk_bf8_f32(acc[m][n][0], acc[m][n][1], 0, false);
      pk     = __builtin_amdgcn_cvt_pk_bf8_f32(acc[m][n][2], acc[m][n][3], pk, true);
      Sb[(size_t)(gr + 0) * NTOK + gc] = (char)(pk & 0xff);
      Sb[(size_t)(gr + 1) * NTOK + gc] = (char)((pk >> 8) & 0xff);
      Sb[(size_t)(gr + 2) * NTOK + gc] = (char)((pk >> 16) & 0xff);
      Sb[(size_t)(gr + 3) * NTOK + gc] = (char)((pk >> 24) & 0xff);
      if (!diag) {
        *reinterpret_cast<int*>(Sb + (size_t)gc * NTOK + gr) = pk;
      }
    }
  }
}

// Row softmax: ONE WAVE PER ROW, zero barriers, zero LDS.
// Block = 256 thr = 4 waves = 4 rows; lane owns 32 e5m2 (32 B load,
// 128 B contiguous f32 store). Reduce via __shfl_xor only.
__global__ __launch_bounds__(256) void softmax_wave_kernel(
    const char* __restrict__ S8, float* __restrict__ P) {
  const int rid  = blockIdx.x * 4 + (threadIdx.x >> 6);  // global row id 0..16383
  const int b    = rid & 7;                              // batch (XCD pin)
  const int row  = rid >> 3;
  const int lane = threadIdx.x & 63;

  const char* srow = S8 + ((size_t)b * NTOK + row) * NTOK;
  float* prow = P + ((size_t)b * NTOK + row) * NTOK;

  // load 32 e5m2 = 32 B (two int4)
  const int4 h0 = *reinterpret_cast<const int4*>(srow + lane * 32);
  const int4 h1 = *reinterpret_cast<const int4*>(srow + lane * 32 + 16);
  unsigned wds[8] = {(unsigned)h0.x, (unsigned)h0.y, (unsigned)h0.z, (unsigned)h0.w,
                     (unsigned)h1.x, (unsigned)h1.y, (unsigned)h1.z, (unsigned)h1.w};
  float v[32];
#pragma unroll
  for (int q = 0; q < 8; ++q)
#pragma unroll
    for (int k = 0; k < 4; ++k)
      v[q * 4 + k] = e5m2tof((wds[q] >> (8 * k)) & 0xff);

  float m = v[0];
#pragma unroll
  for (int k = 1; k < 32; ++k) m = fmaxf(m, v[k]);
#pragma unroll
  for (int off = 32; off > 0; off >>= 1) m = fmaxf(m, __shfl_xor(m, off));

  float s = 0.f;
#pragma unroll
  for (int k = 0; k < 32; ++k) { v[k] = __expf(v[k] - m); s += v[k]; }
#pragma unroll
  for (int off = 32; off > 0; off >>= 1) s += __shfl_xor(s, off);

  const float inv = 1.0f / s;
  float* outp = prow + lane * 32;
#pragma unroll
  for (int q = 0; q < 8; ++q) {
    f32x4 o;
    o[0] = v[q * 4 + 0] * inv;
    o[1] = v[q * 4 + 1] * inv;
    o[2] = v[q * 4 + 2] * inv;
    o[3] = v[q * 4 + 3] * inv;
    *reinterpret_cast<f32x4*>(outp + q * 4) = o;
  }
}

// ---------- fallback path (ws too small): round-1 verified kernels ----------
__global__ __launch_bounds__(256) void scores_kernel(const float* __restrict__ X,
                                                     float* __restrict__ S) {
  const int b  = blockIdx.z;
  const int i0 = blockIdx.y * 128;
  const int j0 = blockIdx.x * 128;
  const float* Xb = X + (size_t)b * NTOK * DDIM;
  float* Sb = S + (size_t)b * NTOK * NTOK;

  __shared__ short lds_a[128][64];
  __shared__ short lds_b[128][64];

  const int t    = threadIdx.x;
  const int lane = t & 63;
  const int w    = t >> 6;
  const int wr   = (w >> 1) * 64;
  const int wc   = (w & 1) * 64;
  const int lr   = lane & 15;
  const int lk   = (lane >> 4) * 8;

  f32x4 acc[4][4] = {};

  for (int k0 = 0; k0 < DDIM; k0 += 64) {
#pragma unroll
    for (int q = 0; q < 8; ++q) {
      const int v  = t + 256 * q;
      const int r  = v >> 4;
      const int c4 = (v & 15) * 4;
      const float4 va = *reinterpret_cast<const float4*>(
          Xb + (size_t)(i0 + r) * DDIM + k0 + c4);
      const float4 vb = *reinterpret_cast<const float4*>(
          Xb + (size_t)(j0 + r) * DDIM + k0 + c4);
      short4 sa, sb;
      sa.x = f2bf(va.x); sa.y = f2bf(va.y); sa.z = f2bf(va.z); sa.w = f2bf(va.w);
      sb.x = f2bf(vb.x); sb.y = f2bf(vb.y); sb.z = f2bf(vb.z); sb.w = f2bf(vb.w);
      *reinterpret_cast<short4*>(&lds_a[r][c4]) = sa;
      *reinterpret_cast<short4*>(&lds_b[r][c4]) = sb;
    }
    __syncthreads();

#pragma unroll
    for (int ks = 0; ks < 2; ++ks) {
      bf16x8 af[4], bfr[4];
#pragma unroll
      for (int m = 0; m < 4; ++m)
        af[m] = *reinterpret_cast<const bf16x8*>(&lds_a[wr + m * 16 + lr][ks * 32 + lk]);
#pragma unroll
      for (int n = 0; n < 4; ++n)
        bfr[n] = *reinterpret_cast<const bf16x8*>(&lds_b[wc + n * 16 + lr][ks * 32 + lk]);
#pragma unroll
      for (int m = 0; m < 4; ++m)
#pragma unroll
        for (int n = 0; n < 4; ++n)
          acc[m][n] = __builtin_amdgcn_mfma_f32_16x16x32_bf16(af[m], bfr[n], acc[m][n], 0, 0, 0);
    }
    __syncthreads();
  }

  const int crow = (lane >> 4) * 4;
  const int ccol = lane & 15;
#pragma unroll
  for (int m = 0; m < 4; ++m) {
#pragma unroll
    for (int n = 0; n < 4; ++n) {
      const int gr = i0 + wr + m * 16 + crow;
      const int gc = j0 + wc + n * 16 + ccol;
      float* outp = Sb + (size_t)gr * NTOK + gc;
#pragma unroll
      for (int r = 0; r < 4; ++r)
        outp[(size_t)r * NTOK] = acc[m][n][r];
    }
  }
}

// In-place row softmax: one 256-thread block per row of 2048 fp32.
__global__ __launch_bounds__(256) void softmax_kernel(float* __restrict__ S) {
  float* row = S + (size_t)blockIdx.x * NTOK;
  const int t    = threadIdx.x;
  const int lane = t & 63;
  const int w    = t >> 6;

  float4* rv = reinterpret_cast<float4*>(row);
  float4 a = rv[t];
  float4 b = rv[t + 256];

  float m = fmaxf(fmaxf(fmaxf(a.x, a.y), fmaxf(a.z, a.w)),
                  fmaxf(fmaxf(b.x, b.y), fmaxf(b.z, b.w)));
#pragma unroll
  for (int off = 32; off > 0; off >>= 1) m = fmaxf(m, __shfl_xor(m, off));

  __shared__ float redm[4];
  __shared__ float reds[4];
  if (lane == 0) redm[w] = m;
  __syncthreads();
  m = fmaxf(fmaxf(redm[0], redm[1]), fmaxf(redm[2], redm[3]));

  a.x = __expf(a.x - m); a.y = __expf(a.y - m);
  a.z = __expf(a.z - m); a.w = __expf(a.w - m);
  b.x = __expf(b.x - m); b.y = __expf(b.y - m);
  b.z = __expf(b.z - m); b.w = __expf(b.w - m);

  float s = (a.x + a.y + a.z + a.w) + (b.x + b.y + b.z + b.w);
#pragma unroll
  for (int off = 32; off > 0; off >>= 1) s += __shfl_xor(s, off);
  if (lane == 0) reds[w] = s;
  __syncthreads();
  s = reds[0] + reds[1] + reds[2] + reds[3];

  const float inv = 1.0f / s;
  a.x *= inv; a.y *= inv; a.z *= inv; a.w *= inv;
  b.x *= inv; b.y *= inv; b.z *= inv; b.w *= inv;
  rv[t] = a;
  rv[t + 256] = b;
}

extern "C" void kernel_launch(void* const* d_in, const int* in_sizes, int n_in,
                              void* d_out, int out_size, void* d_ws, size_t ws_size,
                              hipStream_t stream) {
  const float* X = (const float*)d_in[0];
  float* out = (float*)d_out;

  const size_t offS = 32u << 20;   // S8 at +32 MB (X8 is 8.4 MB)
  const size_t need = offS + (size_t)NBATCH * NTOK * NTOK;  // ~66 MB

  if (ws_size >= need) {
    char* X8 = (char*)d_ws;
    char* S8 = (char*)d_ws + offS;
    const int n_threads = NBATCH * NTOK * DDIM / 8;
    convert_fp8_kernel<<<n_threads / 256, 256, 0, stream>>>(X, X8);
    // 136 triangular 128x128 tiles x 8 batches; bid&7 = batch (XCD pin)
    scores_fp8_kernel<<<136 * NBATCH, 256, 0, stream>>>(X8, S8);
    // 16384 rows / 4 rows per block
    softmax_wave_kernel<<<NBATCH * NTOK / 4, 256, 0, stream>>>(S8, out);
  } else {
    dim3 ggrid(NTOK / 128, NTOK / 128, NBATCH);
    scores_kernel<<<ggrid, 256, 0, stream>>>(X, out);
    softmax_kernel<<<NBATCH * NTOK, 256, 0, stream>>>(out);
  }
}

// Round 19
// 62.821 us; speedup vs baseline: 1.3922x; 1.3922x over previous
//
#include <hip/hip_runtime.h>
#include <hip/hip_bf16.h>
#include <hip/hip_fp16.h>

#define NTOK 2048
#define DDIM 512
#define NBATCH 8

using bf16x8 = __attribute__((ext_vector_type(8))) short;
using f32x4  = __attribute__((ext_vector_type(4))) float;

__device__ __forceinline__ short f2bf(float f) {
  __hip_bfloat16 h = __float2bfloat16(f);
  union { __hip_bfloat16 h; short s; } u; u.h = h;
  return u.s;
}

__device__ __forceinline__ float e5m2tof(unsigned byte) {
  // e5m2 is f16 truncated to its top 8 bits
  union { unsigned short u; __half h; } c;
  c.u = (unsigned short)(byte << 8);
  return __half2float(c.h);
}

__device__ __forceinline__ void async_copy16(void* lds, const void* g) {
  __builtin_amdgcn_global_load_lds(
      (const __attribute__((address_space(1))) void*)g,
      (__attribute__((address_space(3))) void*)lds,
      16, 0, 0);
}

// fp32 -> fp8 e4m3 (OCP) convert: each thread 8 floats -> 8 B store.
__global__ __launch_bounds__(256) void convert_fp8_kernel(const float* __restrict__ X,
                                                          char* __restrict__ Y) {
  const int i = blockIdx.x * 256 + threadIdx.x;
  const float4* xv = reinterpret_cast<const float4*>(X);
  const float4 a = xv[(size_t)i * 2];
  const float4 b = xv[(size_t)i * 2 + 1];
  int lo = __builtin_amdgcn_cvt_pk_fp8_f32(a.x, a.y, 0, false);
  lo     = __builtin_amdgcn_cvt_pk_fp8_f32(a.z, a.w, lo, true);
  int hi = __builtin_amdgcn_cvt_pk_fp8_f32(b.x, b.y, 0, false);
  hi     = __builtin_amdgcn_cvt_pk_fp8_f32(b.z, b.w, hi, true);
  int2 o; o.x = lo; o.y = hi;
  *reinterpret_cast<int2*>(Y + (size_t)i * 8) = o;
}

// Symmetric scores on fp8-e4m3 (r17 champion, unchanged): 128x128 tile,
// 4 waves, BK=64 + XOR swizzle, 3-slot ring, one barrier per K-step,
// e5m2 output, diag alias B->A.
__global__ __launch_bounds__(256, 4) void scores_fp8_kernel(
    const char* __restrict__ X8, char* __restrict__ S8) {
  int rem = blockIdx.x >> 3;
  int bi = 0;
  while (rem >= 16 - bi) { rem -= 16 - bi; ++bi; }
  const int bj = bi + rem;
  const int b  = blockIdx.x & 7;           // batch -> XCD pin
  const bool diag = (bi == bj);

  const int i0 = bi * 128;
  const int j0 = bj * 128;
  const char* Xb = X8 + (size_t)b * NTOK * DDIM;   // 512 B per row
  char* Sb = S8 + (size_t)b * NTOK * NTOK;         // 1 B per score

  __shared__ char ldsA8[3][128 * 64];      // 8 KB per slot
  __shared__ char ldsB8[3][128 * 64];      // total 48 KB

  const int t    = threadIdx.x;
  const int lane = t & 63;
  const int w    = t >> 6;                 // 0..3
  const int wr   = (w >> 1) * 64;
  const int wc   = (w & 1) * 64;
  const int lr   = lane & 15;
  const int g    = lane >> 4;              // 0..3
  const int s4   = (lr >> 2) & 3;          // read-side swizzle key (row>>2)&3
  const int ko0  = (((g >> 1) ^ s4) * 16) + (g & 1) * 8;
  const int ko1  = (((2 + (g >> 1)) ^ s4) * 16) + (g & 1) * 8;

  f32x4 acc[4][4] = {};

  auto stage8 = [&](int slot, int kt) {
    const int k0 = kt * 64;                // 64 B per row per K-step
#pragma unroll
    for (int q = 0; q < 2; ++q) {
      const int seg  = w * 2 + q;          // 8 segs of 1 KB (16 rows x 64 B)
      const int row  = seg * 16 + (lane >> 2);
      const int csrc = ((lane & 3) ^ ((row >> 2) & 3)) * 16;  // inverse swizzle
      async_copy16(&ldsA8[slot][seg * 1024],
                   Xb + (size_t)(i0 + row) * DDIM + k0 + csrc);
      if (!diag)
        async_copy16(&ldsB8[slot][seg * 1024],
                     Xb + (size_t)(j0 + row) * DDIM + k0 + csrc);
    }
  };

  auto phases8 = [&](int slot) {
    const char* A0 = ldsA8[slot];
    const char* B0 = diag ? ldsA8[slot] : ldsB8[slot];
#pragma unroll
    for (int ks = 0; ks < 2; ++ks) {
      const int ko = ks ? ko1 : ko0;
      long long af0 = *reinterpret_cast<const long long*>(&A0[(wr + 0 * 16 + lr) * 64 + ko]);
      long long af1 = *reinterpret_cast<const long long*>(&A0[(wr + 1 * 16 + lr) * 64 + ko]);
      long long af2 = *reinterpret_cast<const long long*>(&A0[(wr + 2 * 16 + lr) * 64 + ko]);
      long long af3 = *reinterpret_cast<const long long*>(&A0[(wr + 3 * 16 + lr) * 64 + ko]);
      long long bf0 = *reinterpret_cast<const long long*>(&B0[(wc + 0 * 16 + lr) * 64 + ko]);
      long long bf1 = *reinterpret_cast<const long long*>(&B0[(wc + 1 * 16 + lr) * 64 + ko]);
      long long bf2 = *reinterpret_cast<const long long*>(&B0[(wc + 2 * 16 + lr) * 64 + ko]);
      long long bf3 = *reinterpret_cast<const long long*>(&B0[(wc + 3 * 16 + lr) * 64 + ko]);
      __builtin_amdgcn_s_setprio(1);
      acc[0][0] = __builtin_amdgcn_mfma_f32_16x16x32_fp8_fp8(af0, bf0, acc[0][0], 0, 0, 0);
      acc[0][1] = __builtin_amdgcn_mfma_f32_16x16x32_fp8_fp8(af0, bf1, acc[0][1], 0, 0, 0);
      acc[0][2] = __builtin_amdgcn_mfma_f32_16x16x32_fp8_fp8(af0, bf2, acc[0][2], 0, 0, 0);
      acc[0][3] = __builtin_amdgcn_mfma_f32_16x16x32_fp8_fp8(af0, bf3, acc[0][3], 0, 0, 0);
      acc[1][0] = __builtin_amdgcn_mfma_f32_16x16x32_fp8_fp8(af1, bf0, acc[1][0], 0, 0, 0);
      acc[1][1] = __builtin_amdgcn_mfma_f32_16x16x32_fp8_fp8(af1, bf1, acc[1][1], 0, 0, 0);
      acc[1][2] = __builtin_amdgcn_mfma_f32_16x16x32_fp8_fp8(af1, bf2, acc[1][2], 0, 0, 0);
      acc[1][3] = __builtin_amdgcn_mfma_f32_16x16x32_fp8_fp8(af1, bf3, acc[1][3], 0, 0, 0);
      acc[2][0] = __builtin_amdgcn_mfma_f32_16x16x32_fp8_fp8(af2, bf0, acc[2][0], 0, 0, 0);
      acc[2][1] = __builtin_amdgcn_mfma_f32_16x16x32_fp8_fp8(af2, bf1, acc[2][1], 0, 0, 0);
      acc[2][2] = __builtin_amdgcn_mfma_f32_16x16x32_fp8_fp8(af2, bf2, acc[2][2], 0, 0, 0);
      acc[2][3] = __builtin_amdgcn_mfma_f32_16x16x32_fp8_fp8(af2, bf3, acc[2][3], 0, 0, 0);
      acc[3][0] = __builtin_amdgcn_mfma_f32_16x16x32_fp8_fp8(af3, bf0, acc[3][0], 0, 0, 0);
      acc[3][1] = __builtin_amdgcn_mfma_f32_16x16x32_fp8_fp8(af3, bf1, acc[3][1], 0, 0, 0);
      acc[3][2] = __builtin_amdgcn_mfma_f32_16x16x32_fp8_fp8(af3, bf2, acc[3][2], 0, 0, 0);
      acc[3][3] = __builtin_amdgcn_mfma_f32_16x16x32_fp8_fp8(af3, bf3, acc[3][3], 0, 0, 0);
      __builtin_amdgcn_s_setprio(0);
    }
  };

  // prologue: stage kt=0 into slot 0 (prefetch depth 1)
  stage8(0, 0);
#pragma unroll
  for (int i = 0; i < 8; ++i) {
    if (i + 1 < 8) {
      stage8((i + 1) % 3, i + 1);          // issue next-tile loads first
      if (diag) { asm volatile("s_waitcnt vmcnt(2)" ::: "memory"); }
      else      { asm volatile("s_waitcnt vmcnt(4)" ::: "memory"); }
    } else {
      asm volatile("s_waitcnt vmcnt(0)" ::: "memory");
    }
    __builtin_amdgcn_s_barrier();          // slot i visible to all waves
    phases8(i % 3);                        // single barrier per K-step
  }

  // epilogue: C/D layout col = lane&15, row = (lane>>4)*4 + reg.
  const int crow = (lane >> 4) * 4;
  const int ccol = lane & 15;

#pragma unroll
  for (int m = 0; m < 4; ++m) {
#pragma unroll
    for (int n = 0; n < 4; ++n) {
      const int gr = i0 + wr + m * 16 + crow;   // multiple of 4
      const int gc = j0 + wc + n * 16 + ccol;
      int pk = __builtin_amdgcn_cvt_pk_bf8_f32(acc[m][n][0], acc[m][n][1], 0, false);
      pk     = __builtin_amdgcn_cvt_pk_bf8_f32(acc[m][n][2], acc[m][n][3], pk, true);
      Sb[(size_t)(gr + 0) * NTOK + gc] = (char)(pk & 0xff);
      Sb[(size_t)(gr + 1) * NTOK + gc] = (char)((pk >> 8) & 0xff);
      Sb[(size_t)(gr + 2) * NTOK + gc] = (char)((pk >> 16) & 0xff);
      Sb[(size_t)(gr + 3) * NTOK + gc] = (char)((pk >> 24) & 0xff);
      if (!diag) {
        *reinterpret_cast<int*>(Sb + (size_t)gc * NTOK + gr) = pk;
      }
    }
  }
}

// Row softmax: one wave per row, zero barriers/LDS, INTERLEAVED layout.
// Lane owns cols lane*4 + c*256 (c=0..7): every load instruction is 256 B
// contiguous, every f32x4 store instruction is 1 KB contiguous (fixes the
// r18 regression, which used lane-contiguous chunks at 128 B stride).
__global__ __launch_bounds__(256) void softmax_wave_kernel(
    const char* __restrict__ S8, float* __restrict__ P) {
  const int rid  = blockIdx.x * 4 + (threadIdx.x >> 6);  // global row id
  const int b    = rid & 7;                              // batch (XCD pin)
  const int row  = rid >> 3;
  const int lane = threadIdx.x & 63;

  const char* srow = S8 + ((size_t)b * NTOK + row) * NTOK;
  float* prow = P + ((size_t)b * NTOK + row) * NTOK;

  unsigned wds[8];
#pragma unroll
  for (int c = 0; c < 8; ++c)
    wds[c] = *reinterpret_cast<const unsigned*>(srow + lane * 4 + c * 256);

  float v[32];
#pragma unroll
  for (int c = 0; c < 8; ++c)
#pragma unroll
    for (int k = 0; k < 4; ++k)
      v[c * 4 + k] = e5m2tof((wds[c] >> (8 * k)) & 0xff);

  float m = v[0];
#pragma unroll
  for (int k = 1; k < 32; ++k) m = fmaxf(m, v[k]);
#pragma unroll
  for (int off = 32; off > 0; off >>= 1) m = fmaxf(m, __shfl_xor(m, off));

  float s = 0.f;
#pragma unroll
  for (int k = 0; k < 32; ++k) { v[k] = __expf(v[k] - m); s += v[k]; }
#pragma unroll
  for (int off = 32; off > 0; off >>= 1) s += __shfl_xor(s, off);

  const float inv = 1.0f / s;
#pragma unroll
  for (int c = 0; c < 8; ++c) {
    f32x4 o;
    o[0] = v[c * 4 + 0] * inv;
    o[1] = v[c * 4 + 1] * inv;
    o[2] = v[c * 4 + 2] * inv;
    o[3] = v[c * 4 + 3] * inv;
    *reinterpret_cast<f32x4*>(prow + lane * 4 + c * 256) = o;
  }
}

// ---------- fallback path (ws too small): round-1 verified kernels ----------
__global__ __launch_bounds__(256) void scores_kernel(const float* __restrict__ X,
                                                     float* __restrict__ S) {
  const int b  = blockIdx.z;
  const int i0 = blockIdx.y * 128;
  const int j0 = blockIdx.x * 128;
  const float* Xb = X + (size_t)b * NTOK * DDIM;
  float* Sb = S + (size_t)b * NTOK * NTOK;

  __shared__ short lds_a[128][64];
  __shared__ short lds_b[128][64];

  const int t    = threadIdx.x;
  const int lane = t & 63;
  const int w    = t >> 6;
  const int wr   = (w >> 1) * 64;
  const int wc   = (w & 1) * 64;
  const int lr   = lane & 15;
  const int lk   = (lane >> 4) * 8;

  f32x4 acc[4][4] = {};

  for (int k0 = 0; k0 < DDIM; k0 += 64) {
#pragma unroll
    for (int q = 0; q < 8; ++q) {
      const int v  = t + 256 * q;
      const int r  = v >> 4;
      const int c4 = (v & 15) * 4;
      const float4 va = *reinterpret_cast<const float4*>(
          Xb + (size_t)(i0 + r) * DDIM + k0 + c4);
      const float4 vb = *reinterpret_cast<const float4*>(
          Xb + (size_t)(j0 + r) * DDIM + k0 + c4);
      short4 sa, sb;
      sa.x = f2bf(va.x); sa.y = f2bf(va.y); sa.z = f2bf(va.z); sa.w = f2bf(va.w);
      sb.x = f2bf(vb.x); sb.y = f2bf(vb.y); sb.z = f2bf(vb.z); sb.w = f2bf(vb.w);
      *reinterpret_cast<short4*>(&lds_a[r][c4]) = sa;
      *reinterpret_cast<short4*>(&lds_b[r][c4]) = sb;
    }
    __syncthreads();

#pragma unroll
    for (int ks = 0; ks < 2; ++ks) {
      bf16x8 af[4], bfr[4];
#pragma unroll
      for (int m = 0; m < 4; ++m)
        af[m] = *reinterpret_cast<const bf16x8*>(&lds_a[wr + m * 16 + lr][ks * 32 + lk]);
#pragma unroll
      for (int n = 0; n < 4; ++n)
        bfr[n] = *reinterpret_cast<const bf16x8*>(&lds_b[wc + n * 16 + lr][ks * 32 + lk]);
#pragma unroll
      for (int m = 0; m < 4; ++m)
#pragma unroll
        for (int n = 0; n < 4; ++n)
          acc[m][n] = __builtin_amdgcn_mfma_f32_16x16x32_bf16(af[m], bfr[n], acc[m][n], 0, 0, 0);
    }
    __syncthreads();
  }

  const int crow = (lane >> 4) * 4;
  const int ccol = lane & 15;
#pragma unroll
  for (int m = 0; m < 4; ++m) {
#pragma unroll
    for (int n = 0; n < 4; ++n) {
      const int gr = i0 + wr + m * 16 + crow;
      const int gc = j0 + wc + n * 16 + ccol;
      float* outp = Sb + (size_t)gr * NTOK + gc;
#pragma unroll
      for (int r = 0; r < 4; ++r)
        outp[(size_t)r * NTOK] = acc[m][n][r];
    }
  }
}

// In-place row softmax: one 256-thread block per row of 2048 fp32.
__global__ __launch_bounds__(256) void softmax_kernel(float* __restrict__ S) {
  float* row = S + (size_t)blockIdx.x * NTOK;
  const int t    = threadIdx.x;
  const int lane = t & 63;
  const int w    = t >> 6;

  float4* rv = reinterpret_cast<float4*>(row);
  float4 a = rv[t];
  float4 b = rv[t + 256];

  float m = fmaxf(fmaxf(fmaxf(a.x, a.y), fmaxf(a.z, a.w)),
                  fmaxf(fmaxf(b.x, b.y), fmaxf(b.z, b.w)));
#pragma unroll
  for (int off = 32; off > 0; off >>= 1) m = fmaxf(m, __shfl_xor(m, off));

  __shared__ float redm[4];
  __shared__ float reds[4];
  if (lane == 0) redm[w] = m;
  __syncthreads();
  m = fmaxf(fmaxf(redm[0], redm[1]), fmaxf(redm[2], redm[3]));

  a.x = __expf(a.x - m); a.y = __expf(a.y - m);
  a.z = __expf(a.z - m); a.w = __expf(a.w - m);
  b.x = __expf(b.x - m); b.y = __expf(b.y - m);
  b.z = __expf(b.z - m); b.w = __expf(b.w - m);

  float s = (a.x + a.y + a.z + a.w) + (b.x + b.y + b.z + b.w);
#pragma unroll
  for (int off = 32; off > 0; off >>= 1) s += __shfl_xor(s, off);
  if (lane == 0) reds[w] = s;
  __syncthreads();
  s = reds[0] + reds[1] + reds[2] + reds[3];

  const float inv = 1.0f / s;
  a.x *= inv; a.y *= inv; a.z *= inv; a.w *= inv;
  b.x *= inv; b.y *= inv; b.z *= inv; b.w *= inv;
  rv[t] = a;
  rv[t + 256] = b;
}

extern "C" void kernel_launch(void* const* d_in, const int* in_sizes, int n_in,
                              void* d_out, int out_size, void* d_ws, size_t ws_size,
                              hipStream_t stream) {
  const float* X = (const float*)d_in[0];
  float* out = (float*)d_out;

  const size_t offS = 32u << 20;   // S8 at +32 MB (X8 is 8.4 MB)
  const size_t need = offS + (size_t)NBATCH * NTOK * NTOK;  // ~66 MB

  if (ws_size >= need) {
    char* X8 = (char*)d_ws;
    char* S8 = (char*)d_ws + offS;
    const int n_threads = NBATCH * NTOK * DDIM / 8;
    convert_fp8_kernel<<<n_threads / 256, 256, 0, stream>>>(X, X8);
    // 136 triangular 128x128 tiles x 8 batches; bid&7 = batch (XCD pin)
    scores_fp8_kernel<<<136 * NBATCH, 256, 0, stream>>>(X8, S8);
    // 16384 rows / 4 rows per block; interleaved coalesced layout
    softmax_wave_kernel<<<NBATCH * NTOK / 4, 256, 0, stream>>>(S8, out);
  } else {
    dim3 ggrid(NTOK / 128, NTOK / 128, NBATCH);
    scores_kernel<<<ggrid, 256, 0, stream>>>(X, out);
    softmax_kernel<<<NBATCH * NTOK, 256, 0, stream>>>(out);
  }
}

// Round 20
// 61.069 us; speedup vs baseline: 1.4322x; 1.0287x over previous
//
#include <hip/hip_runtime.h>
#include <hip/hip_bf16.h>
#include <hip/hip_fp16.h>

#define NTOK 2048
#define DDIM 512
#define NBATCH 8

using bf16x8 = __attribute__((ext_vector_type(8))) short;
using f32x4  = __attribute__((ext_vector_type(4))) float;

__device__ __forceinline__ short f2bf(float f) {
  __hip_bfloat16 h = __float2bfloat16(f);
  union { __hip_bfloat16 h; short s; } u; u.h = h;
  return u.s;
}

__device__ __forceinline__ float e5m2tof(unsigned byte) {
  // e5m2 is f16 truncated to its top 8 bits
  union { unsigned short u; __half h; } c;
  c.u = (unsigned short)(byte << 8);
  return __half2float(c.h);
}

__device__ __forceinline__ void async_copy16(void* lds, const void* g) {
  __builtin_amdgcn_global_load_lds(
      (const __attribute__((address_space(1))) void*)g,
      (__attribute__((address_space(3))) void*)lds,
      16, 0, 0);
}

// fp32 -> fp8 e4m3 (OCP) convert: each thread 8 floats -> 8 B store.
__global__ __launch_bounds__(256) void convert_fp8_kernel(const float* __restrict__ X,
                                                          char* __restrict__ Y) {
  const int i = blockIdx.x * 256 + threadIdx.x;
  const float4* xv = reinterpret_cast<const float4*>(X);
  const float4 a = xv[(size_t)i * 2];
  const float4 b = xv[(size_t)i * 2 + 1];
  int lo = __builtin_amdgcn_cvt_pk_fp8_f32(a.x, a.y, 0, false);
  lo     = __builtin_amdgcn_cvt_pk_fp8_f32(a.z, a.w, lo, true);
  int hi = __builtin_amdgcn_cvt_pk_fp8_f32(b.x, b.y, 0, false);
  hi     = __builtin_amdgcn_cvt_pk_fp8_f32(b.z, b.w, hi, true);
  int2 o; o.x = lo; o.y = hi;
  *reinterpret_cast<int2*>(Y + (size_t)i * 8) = o;
}

// Symmetric scores on fp8-e4m3 (r17/r19 champion structure): 128x128 tile,
// 4 waves, BK=64 + XOR swizzle, 3-slot ring, one barrier per K-step,
// e5m2 output, diag alias B->A.
// NEW (r20): diag-LAST tile ordering. Grid runs ~2 residency rounds
// (768+320); putting all 128 cheap diagonal blocks (half staging, no
// mirror) in the final round reduces the tail imbalance.
//   tid in [0,120): off-diag pair (bi<bj); tid in [120,136): diag tid-120.
__global__ __launch_bounds__(256, 4) void scores_fp8_kernel(
    const char* __restrict__ X8, char* __restrict__ S8) {
  const int tid = blockIdx.x >> 3;
  const int b   = blockIdx.x & 7;          // batch -> XCD pin
  int bi, bj;
  bool diag;
  if (tid < 120) {
    int rem = tid;
    bi = 0;
    while (rem >= 15 - bi) { rem -= 15 - bi; ++bi; }
    bj = bi + 1 + rem;
    diag = false;
  } else {
    bi = bj = tid - 120;
    diag = true;
  }

  const int i0 = bi * 128;
  const int j0 = bj * 128;
  const char* Xb = X8 + (size_t)b * NTOK * DDIM;   // 512 B per row
  char* Sb = S8 + (size_t)b * NTOK * NTOK;         // 1 B per score

  __shared__ char ldsA8[3][128 * 64];      // 8 KB per slot
  __shared__ char ldsB8[3][128 * 64];      // total 48 KB

  const int t    = threadIdx.x;
  const int lane = t & 63;
  const int w    = t >> 6;                 // 0..3
  const int wr   = (w >> 1) * 64;
  const int wc   = (w & 1) * 64;
  const int lr   = lane & 15;
  const int g    = lane >> 4;              // 0..3
  const int s4   = (lr >> 2) & 3;          // read-side swizzle key (row>>2)&3
  const int ko0  = (((g >> 1) ^ s4) * 16) + (g & 1) * 8;
  const int ko1  = (((2 + (g >> 1)) ^ s4) * 16) + (g & 1) * 8;

  f32x4 acc[4][4] = {};

  auto stage8 = [&](int slot, int kt) {
    const int k0 = kt * 64;                // 64 B per row per K-step
#pragma unroll
    for (int q = 0; q < 2; ++q) {
      const int seg  = w * 2 + q;          // 8 segs of 1 KB (16 rows x 64 B)
      const int row  = seg * 16 + (lane >> 2);
      const int csrc = ((lane & 3) ^ ((row >> 2) & 3)) * 16;  // inverse swizzle
      async_copy16(&ldsA8[slot][seg * 1024],
                   Xb + (size_t)(i0 + row) * DDIM + k0 + csrc);
      if (!diag)
        async_copy16(&ldsB8[slot][seg * 1024],
                     Xb + (size_t)(j0 + row) * DDIM + k0 + csrc);
    }
  };

  auto phases8 = [&](int slot) {
    const char* A0 = ldsA8[slot];
    const char* B0 = diag ? ldsA8[slot] : ldsB8[slot];
#pragma unroll
    for (int ks = 0; ks < 2; ++ks) {
      const int ko = ks ? ko1 : ko0;
      long long af0 = *reinterpret_cast<const long long*>(&A0[(wr + 0 * 16 + lr) * 64 + ko]);
      long long af1 = *reinterpret_cast<const long long*>(&A0[(wr + 1 * 16 + lr) * 64 + ko]);
      long long af2 = *reinterpret_cast<const long long*>(&A0[(wr + 2 * 16 + lr) * 64 + ko]);
      long long af3 = *reinterpret_cast<const long long*>(&A0[(wr + 3 * 16 + lr) * 64 + ko]);
      long long bf0 = *reinterpret_cast<const long long*>(&B0[(wc + 0 * 16 + lr) * 64 + ko]);
      long long bf1 = *reinterpret_cast<const long long*>(&B0[(wc + 1 * 16 + lr) * 64 + ko]);
      long long bf2 = *reinterpret_cast<const long long*>(&B0[(wc + 2 * 16 + lr) * 64 + ko]);
      long long bf3 = *reinterpret_cast<const long long*>(&B0[(wc + 3 * 16 + lr) * 64 + ko]);
      __builtin_amdgcn_s_setprio(1);
      acc[0][0] = __builtin_amdgcn_mfma_f32_16x16x32_fp8_fp8(af0, bf0, acc[0][0], 0, 0, 0);
      acc[0][1] = __builtin_amdgcn_mfma_f32_16x16x32_fp8_fp8(af0, bf1, acc[0][1], 0, 0, 0);
      acc[0][2] = __builtin_amdgcn_mfma_f32_16x16x32_fp8_fp8(af0, bf2, acc[0][2], 0, 0, 0);
      acc[0][3] = __builtin_amdgcn_mfma_f32_16x16x32_fp8_fp8(af0, bf3, acc[0][3], 0, 0, 0);
      acc[1][0] = __builtin_amdgcn_mfma_f32_16x16x32_fp8_fp8(af1, bf0, acc[1][0], 0, 0, 0);
      acc[1][1] = __builtin_amdgcn_mfma_f32_16x16x32_fp8_fp8(af1, bf1, acc[1][1], 0, 0, 0);
      acc[1][2] = __builtin_amdgcn_mfma_f32_16x16x32_fp8_fp8(af1, bf2, acc[1][2], 0, 0, 0);
      acc[1][3] = __builtin_amdgcn_mfma_f32_16x16x32_fp8_fp8(af1, bf3, acc[1][3], 0, 0, 0);
      acc[2][0] = __builtin_amdgcn_mfma_f32_16x16x32_fp8_fp8(af2, bf0, acc[2][0], 0, 0, 0);
      acc[2][1] = __builtin_amdgcn_mfma_f32_16x16x32_fp8_fp8(af2, bf1, acc[2][1], 0, 0, 0);
      acc[2][2] = __builtin_amdgcn_mfma_f32_16x16x32_fp8_fp8(af2, bf2, acc[2][2], 0, 0, 0);
      acc[2][3] = __builtin_amdgcn_mfma_f32_16x16x32_fp8_fp8(af2, bf3, acc[2][3], 0, 0, 0);
      acc[3][0] = __builtin_amdgcn_mfma_f32_16x16x32_fp8_fp8(af3, bf0, acc[3][0], 0, 0, 0);
      acc[3][1] = __builtin_amdgcn_mfma_f32_16x16x32_fp8_fp8(af3, bf1, acc[3][1], 0, 0, 0);
      acc[3][2] = __builtin_amdgcn_mfma_f32_16x16x32_fp8_fp8(af3, bf2, acc[3][2], 0, 0, 0);
      acc[3][3] = __builtin_amdgcn_mfma_f32_16x16x32_fp8_fp8(af3, bf3, acc[3][3], 0, 0, 0);
      __builtin_amdgcn_s_setprio(0);
    }
  };

  // prologue: stage kt=0 into slot 0 (prefetch depth 1)
  stage8(0, 0);
#pragma unroll
  for (int i = 0; i < 8; ++i) {
    if (i + 1 < 8) {
      stage8((i + 1) % 3, i + 1);          // issue next-tile loads first
      if (diag) { asm volatile("s_waitcnt vmcnt(2)" ::: "memory"); }
      else      { asm volatile("s_waitcnt vmcnt(4)" ::: "memory"); }
    } else {
      asm volatile("s_waitcnt vmcnt(0)" ::: "memory");
    }
    __builtin_amdgcn_s_barrier();          // slot i visible to all waves
    phases8(i % 3);                        // single barrier per K-step
  }

  // epilogue: C/D layout col = lane&15, row = (lane>>4)*4 + reg.
  const int crow = (lane >> 4) * 4;
  const int ccol = lane & 15;

#pragma unroll
  for (int m = 0; m < 4; ++m) {
#pragma unroll
    for (int n = 0; n < 4; ++n) {
      const int gr = i0 + wr + m * 16 + crow;   // multiple of 4
      const int gc = j0 + wc + n * 16 + ccol;
      int pk = __builtin_amdgcn_cvt_pk_bf8_f32(acc[m][n][0], acc[m][n][1], 0, false);
      pk     = __builtin_amdgcn_cvt_pk_bf8_f32(acc[m][n][2], acc[m][n][3], pk, true);
      Sb[(size_t)(gr + 0) * NTOK + gc] = (char)(pk & 0xff);
      Sb[(size_t)(gr + 1) * NTOK + gc] = (char)((pk >> 8) & 0xff);
      Sb[(size_t)(gr + 2) * NTOK + gc] = (char)((pk >> 16) & 0xff);
      Sb[(size_t)(gr + 3) * NTOK + gc] = (char)((pk >> 24) & 0xff);
      if (!diag) {
        *reinterpret_cast<int*>(Sb + (size_t)gc * NTOK + gr) = pk;
      }
    }
  }
}

// Row softmax: one wave per row, zero barriers/LDS, interleaved layout
// (r19-verified): lane owns cols lane*4 + c*256; 256 B loads, 1 KB stores.
__global__ __launch_bounds__(256) void softmax_wave_kernel(
    const char* __restrict__ S8, float* __restrict__ P) {
  const int rid  = blockIdx.x * 4 + (threadIdx.x >> 6);  // global row id
  const int b    = rid & 7;                              // batch (XCD pin)
  const int row  = rid >> 3;
  const int lane = threadIdx.x & 63;

  const char* srow = S8 + ((size_t)b * NTOK + row) * NTOK;
  float* prow = P + ((size_t)b * NTOK + row) * NTOK;

  unsigned wds[8];
#pragma unroll
  for (int c = 0; c < 8; ++c)
    wds[c] = *reinterpret_cast<const unsigned*>(srow + lane * 4 + c * 256);

  float v[32];
#pragma unroll
  for (int c = 0; c < 8; ++c)
#pragma unroll
    for (int k = 0; k < 4; ++k)
      v[c * 4 + k] = e5m2tof((wds[c] >> (8 * k)) & 0xff);

  float m = v[0];
#pragma unroll
  for (int k = 1; k < 32; ++k) m = fmaxf(m, v[k]);
#pragma unroll
  for (int off = 32; off > 0; off >>= 1) m = fmaxf(m, __shfl_xor(m, off));

  float s = 0.f;
#pragma unroll
  for (int k = 0; k < 32; ++k) { v[k] = __expf(v[k] - m); s += v[k]; }
#pragma unroll
  for (int off = 32; off > 0; off >>= 1) s += __shfl_xor(s, off);

  const float inv = 1.0f / s;
#pragma unroll
  for (int c = 0; c < 8; ++c) {
    f32x4 o;
    o[0] = v[c * 4 + 0] * inv;
    o[1] = v[c * 4 + 1] * inv;
    o[2] = v[c * 4 + 2] * inv;
    o[3] = v[c * 4 + 3] * inv;
    *reinterpret_cast<f32x4*>(prow + lane * 4 + c * 256) = o;
  }
}

// ---------- fallback path (ws too small): round-1 verified kernels ----------
__global__ __launch_bounds__(256) void scores_kernel(const float* __restrict__ X,
                                                     float* __restrict__ S) {
  const int b  = blockIdx.z;
  const int i0 = blockIdx.y * 128;
  const int j0 = blockIdx.x * 128;
  const float* Xb = X + (size_t)b * NTOK * DDIM;
  float* Sb = S + (size_t)b * NTOK * NTOK;

  __shared__ short lds_a[128][64];
  __shared__ short lds_b[128][64];

  const int t    = threadIdx.x;
  const int lane = t & 63;
  const int w    = t >> 6;
  const int wr   = (w >> 1) * 64;
  const int wc   = (w & 1) * 64;
  const int lr   = lane & 15;
  const int lk   = (lane >> 4) * 8;

  f32x4 acc[4][4] = {};

  for (int k0 = 0; k0 < DDIM; k0 += 64) {
#pragma unroll
    for (int q = 0; q < 8; ++q) {
      const int v  = t + 256 * q;
      const int r  = v >> 4;
      const int c4 = (v & 15) * 4;
      const float4 va = *reinterpret_cast<const float4*>(
          Xb + (size_t)(i0 + r) * DDIM + k0 + c4);
      const float4 vb = *reinterpret_cast<const float4*>(
          Xb + (size_t)(j0 + r) * DDIM + k0 + c4);
      short4 sa, sb;
      sa.x = f2bf(va.x); sa.y = f2bf(va.y); sa.z = f2bf(va.z); sa.w = f2bf(va.w);
      sb.x = f2bf(vb.x); sb.y = f2bf(vb.y); sb.z = f2bf(vb.z); sb.w = f2bf(vb.w);
      *reinterpret_cast<short4*>(&lds_a[r][c4]) = sa;
      *reinterpret_cast<short4*>(&lds_b[r][c4]) = sb;
    }
    __syncthreads();

#pragma unroll
    for (int ks = 0; ks < 2; ++ks) {
      bf16x8 af[4], bfr[4];
#pragma unroll
      for (int m = 0; m < 4; ++m)
        af[m] = *reinterpret_cast<const bf16x8*>(&lds_a[wr + m * 16 + lr][ks * 32 + lk]);
#pragma unroll
      for (int n = 0; n < 4; ++n)
        bfr[n] = *reinterpret_cast<const bf16x8*>(&lds_b[wc + n * 16 + lr][ks * 32 + lk]);
#pragma unroll
      for (int m = 0; m < 4; ++m)
#pragma unroll
        for (int n = 0; n < 4; ++n)
          acc[m][n] = __builtin_amdgcn_mfma_f32_16x16x32_bf16(af[m], bfr[n], acc[m][n], 0, 0, 0);
    }
    __syncthreads();
  }

  const int crow = (lane >> 4) * 4;
  const int ccol = lane & 15;
#pragma unroll
  for (int m = 0; m < 4; ++m) {
#pragma unroll
    for (int n = 0; n < 4; ++n) {
      const int gr = i0 + wr + m * 16 + crow;
      const int gc = j0 + wc + n * 16 + ccol;
      float* outp = Sb + (size_t)gr * NTOK + gc;
#pragma unroll
      for (int r = 0; r < 4; ++r)
        outp[(size_t)r * NTOK] = acc[m][n][r];
    }
  }
}

// In-place row softmax: one 256-thread block per row of 2048 fp32.
__global__ __launch_bounds__(256) void softmax_kernel(float* __restrict__ S) {
  float* row = S + (size_t)blockIdx.x * NTOK;
  const int t    = threadIdx.x;
  const int lane = t & 63;
  const int w    = t >> 6;

  float4* rv = reinterpret_cast<float4*>(row);
  float4 a = rv[t];
  float4 b = rv[t + 256];

  float m = fmaxf(fmaxf(fmaxf(a.x, a.y), fmaxf(a.z, a.w)),
                  fmaxf(fmaxf(b.x, b.y), fmaxf(b.z, b.w)));
#pragma unroll
  for (int off = 32; off > 0; off >>= 1) m = fmaxf(m, __shfl_xor(m, off));

  __shared__ float redm[4];
  __shared__ float reds[4];
  if (lane == 0) redm[w] = m;
  __syncthreads();
  m = fmaxf(fmaxf(redm[0], redm[1]), fmaxf(redm[2], redm[3]));

  a.x = __expf(a.x - m); a.y = __expf(a.y - m);
  a.z = __expf(a.z - m); a.w = __expf(a.w - m);
  b.x = __expf(b.x - m); b.y = __expf(b.y - m);
  b.z = __expf(b.z - m); b.w = __expf(b.w - m);

  float s = (a.x + a.y + a.z + a.w) + (b.x + b.y + b.z + b.w);
#pragma unroll
  for (int off = 32; off > 0; off >>= 1) s += __shfl_xor(s, off);
  if (lane == 0) reds[w] = s;
  __syncthreads();
  s = reds[0] + reds[1] + reds[2] + reds[3];

  const float inv = 1.0f / s;
  a.x *= inv; a.y *= inv; a.z *= inv; a.w *= inv;
  b.x *= inv; b.y *= inv; b.z *= inv; b.w *= inv;
  rv[t] = a;
  rv[t + 256] = b;
}

extern "C" void kernel_launch(void* const* d_in, const int* in_sizes, int n_in,
                              void* d_out, int out_size, void* d_ws, size_t ws_size,
                              hipStream_t stream) {
  const float* X = (const float*)d_in[0];
  float* out = (float*)d_out;

  const size_t offS = 32u << 20;   // S8 at +32 MB (X8 is 8.4 MB)
  const size_t need = offS + (size_t)NBATCH * NTOK * NTOK;  // ~66 MB

  if (ws_size >= need) {
    char* X8 = (char*)d_ws;
    char* S8 = (char*)d_ws + offS;
    const int n_threads = NBATCH * NTOK * DDIM / 8;
    convert_fp8_kernel<<<n_threads / 256, 256, 0, stream>>>(X, X8);
    // 136 tiles x 8 batches, off-diag first / diag last (tail balance)
    scores_fp8_kernel<<<136 * NBATCH, 256, 0, stream>>>(X8, S8);
    // 16384 rows / 4 rows per block; interleaved coalesced layout
    softmax_wave_kernel<<<NBATCH * NTOK / 4, 256, 0, stream>>>(S8, out);
  } else {
    dim3 ggrid(NTOK / 128, NTOK / 128, NBATCH);
    scores_kernel<<<ggrid, 256, 0, stream>>>(X, out);
    softmax_kernel<<<NBATCH * NTOK, 256, 0, stream>>>(out);
  }
}